// Round 4
// baseline (19866.116 us; speedup 1.0000x reference)
//
#include <hip/hip_runtime.h>

#define NS 2058   // supersteps: 2048 + 2*5 skew

typedef __attribute__((ext_vector_type(4))) int   i32x4;
typedef __attribute__((ext_vector_type(8))) short s16x8;
typedef __attribute__((ext_vector_type(4))) float f32x4;

__device__ __forceinline__ unsigned short f2bf(float f) {
  unsigned u = __float_as_uint(f);
  unsigned r = u + 0x7FFFu + ((u >> 16) & 1u);
  return (unsigned short)(r >> 16);
}
__device__ __forceinline__ unsigned pack2bf(float lo, float hi) {
  return (unsigned)f2bf(lo) | ((unsigned)f2bf(hi) << 16);
}
__device__ __forceinline__ float bflo(unsigned u){ return __uint_as_float(u << 16); }
__device__ __forceinline__ float bfhi(unsigned u){ return __uint_as_float(u & 0xFFFF0000u); }

__device__ __forceinline__ float sigm(float x){ return 1.0f / (1.0f + __expf(-x)); }
__device__ __forceinline__ float tanh_(float x){
  float ax = fabsf(x);
  float e  = __expf(-2.0f * ax);
  float t  = (1.0f - e) / (1.0f + e);
  return copysignf(t, x);
}

__device__ __forceinline__ unsigned long long aload(const unsigned long long* p) {
  return __hip_atomic_load(p, __ATOMIC_RELAXED, __HIP_MEMORY_SCOPE_AGENT);
}
__device__ __forceinline__ void astore(unsigned long long* p, unsigned long long v) {
  __hip_atomic_store(p, v, __ATOMIC_RELAXED, __HIP_MEMORY_SCOPE_AGENT);
}

// ---------------- input projection ----------------
__global__ __launch_bounds__(256) void k_inproj(const float* __restrict__ x,
                                                const float* __restrict__ w,
                                                const float* __restrict__ bb,
                                                float* __restrict__ XP) {
  int idx = blockIdx.x * 256 + threadIdx.x;
  int b = idx >> 9, j = idx & 511;
  float acc = bb[j];
#pragma unroll
  for (int k = 0; k < 12; ++k) acc += x[b * 12 + k] * w[j * 12 + k];
  XP[idx] = acc;
}

// ---------------- layer-0 input gates (constant over t) ----------------
__global__ __launch_bounds__(256) void k_xg0(const float* __restrict__ XP,
                                             const float* __restrict__ Wih,
                                             const float* __restrict__ bih,
                                             float* __restrict__ XG0) {
  int idx = blockIdx.x * 256 + threadIdx.x;
  int b = idx & 31;
  int r = idx >> 5;
  const float* wr = Wih + (size_t)r * 512;
  const float* xr = XP + b * 512;
  float acc = bih[r];
  for (int k = 0; k < 512; k += 4) {
    const f32x4 w4 = *(const f32x4*)(wr + k);
    const f32x4 x4 = *(const f32x4*)(xr + k);
    acc += w4[0]*x4[0] + w4[1]*x4[1] + w4[2]*x4[2] + w4[3]*x4[3];
  }
  XG0[b * 2048 + r] = acc;
}

// ---------------- 6-layer pipelined scan, tag-in-data sync ----------------
// WG wgid: layer = wgid>>5, w = wgid&31 owns h-cols [16w,16w+16). Wave = gate.
// All cross-WG data moves as u64 atoms {tag<<32 | bf16-pair}, relaxed agent
// atomics (LLC-coherent). No flags, no release fences, no barrier polls.
__global__ __launch_bounds__(256, 1) void k_pipe(
    const float* __restrict__ Wih, const float* __restrict__ Whh,
    const float* __restrict__ bih, const float* __restrict__ bhh,
    const float* __restrict__ lnS, const float* __restrict__ lnB,
    const float* __restrict__ XG0, const float* __restrict__ XP,
    unsigned long long* __restrict__ Hst,    // [6][2][8192] {tag, h pair}
    unsigned long long* __restrict__ Roll,   // [5][4][8192] {tag, out+res pair}
    unsigned long long* __restrict__ PartS,  // [5][4][32][32] {tag, f32 sum}
    unsigned long long* __restrict__ PartQ,  // [5][4][32][32] {tag, f32 sumsq}
    unsigned* __restrict__ RB,               // [32][2048][256] layer-5 rows
    unsigned* __restrict__ Prog)             // [6][32] consumer progress
{
  __shared__ char smem[65536];
  char* xarea = smem;            // 32 KB: LN'd input row (l>=1) / L0 statics
  char* harea = smem + 32768;    // 32 KB: staged h; [+16K): gacc (l>0); [0,2.3K): LN scratch

  const int tid   = threadIdx.x;
  const int wgid  = blockIdx.x;
  const int layer = wgid >> 5;
  const int w     = wgid & 31;
  const int lane  = tid & 63;
  const int wv    = tid >> 6;    // wave = gate index
  const int j0    = w << 4;
  float* gacc = (float*)(layer == 0 ? (smem + 10240) : (harea + 16384));

  unsigned long long* HstL = Hst + layer * 16384;

  // ---- B-fragment preload ----
  s16x8 bfih[16], bfhh[16];
  {
    const int rcol = lane & 15;
    const int kg   = lane >> 4;
    const size_t rowbase = ((size_t)layer * 2048 + (size_t)(wv * 512 + j0 + rcol)) * 512;
    const float* ihr = Wih + rowbase;
    const float* hhr = Whh + rowbase;
#pragma unroll
    for (int kk = 0; kk < 16; ++kk) {
      const int k0 = kg * 8 + kk * 32;
      s16x8 v2;
#pragma unroll
      for (int j = 0; j < 8; ++j) v2[j] = (short)f2bf(hhr[k0 + j]);
      bfhh[kk] = v2;
      if (layer > 0) {
        s16x8 v1;
#pragma unroll
        for (int j = 0; j < 8; ++j) v1[j] = (short)f2bf(ihr[k0 + j]);
        bfih[kk] = v1;
      }
    }
  }

  const int ub = tid >> 3;            // batch row this thread updates
  const int jp = tid & 7;             // col-pair within WG
  const int kpglob = (j0 >> 1) + jp;  // global u32 pair index

  float bs[4][2];
#pragma unroll
  for (int g = 0; g < 4; ++g)
#pragma unroll
    for (int c = 0; c < 2; ++c) {
      const size_t r = (size_t)layer * 2048 + g * 512 + j0 + 2 * jp + c;
      float vv = bhh[r];
      if (layer > 0) vv += bih[r];    // L0: b_ih folded into XG0
      bs[g][c] = vv;
    }

  float sc0 = 0.f, sc1v = 0.f, bi0 = 0.f, bi1 = 0.f;
  if (layer > 0) {
    sc0  = lnS[(layer - 1) * 512 + 2 * tid];
    sc1v = lnS[(layer - 1) * 512 + 2 * tid + 1];
    bi0  = lnB[(layer - 1) * 512 + 2 * tid];
    bi1  = lnB[(layer - 1) * 512 + 2 * tid + 1];
  }

  if (layer == 0) {
    float* xg0s = (float*)smem;           // [4][32][16]
    float* xps  = (float*)(smem + 8192);  // [32][16]
    for (int i = tid; i < 2048; i += 256) {
      int g = i >> 9, b = (i >> 4) & 31, jl = i & 15;
      xg0s[i] = XG0[b * 2048 + g * 512 + j0 + jl];
    }
    for (int i = tid; i < 512; i += 256) {
      int b = i >> 4, jl = i & 15;
      xps[i] = XP[b * 512 + j0 + jl];
    }
  }
  __syncthreads();

  float xinc0 = 0.f, xinc1 = 0.f;
  if (layer == 0) {
    const float* xps = (const float*)(smem + 8192);
    xinc0 = xps[ub * 16 + 2 * jp];
    xinc1 = xps[ub * 16 + 2 * jp + 1];
  }

  const int rA  = lane & 15;
  const int kg2 = lane >> 4;
  const int swz = (rA & 7) << 4;
  const int ab0 = rA * 1024 + kg2 * 16;
  const int ab1 = ab0 + 16384;

  float creg0 = 0.f, creg1 = 0.f;
  unsigned myC = 0;                 // latched consumer-progress (layers<5)
  const int tbase = -2 * layer;
  const int lane31 = lane & 31;

#pragma unroll 1
  for (int s = 0; s < NS; ++s) {
    const int t = s + tbase;
    const bool act = (0 <= t) && (t < 2048);

    if (act) {
      // ---- back-pressure: Roll slot t&3 reusable when consumer prog >= t-4 ----
      if (layer < 5 && t >= 5) {
        const unsigned need = (unsigned)(t - 4);
        while (!__all((int)(myC >= need))) {
          if (myC < need)
            myC = __hip_atomic_load(Prog + (layer + 1) * 32 + lane31,
                                    __ATOMIC_RELAXED, __HIP_MEMORY_SCOPE_AGENT);
          if (!__all((int)(myC >= need))) __builtin_amdgcn_s_sleep(1);
        }
      }

      // ---- issue tagged h[t] loads (full layer state, rotated by w) ----
      const unsigned long long* hs = HstL + (size_t)(t & 1) * 8192;
      unsigned long long a[32];
#pragma unroll
      for (int it = 0; it < 32; ++it) {
        const int q = (it + w) & 31;
        a[it] = aload(hs + q * 256 + tid);
      }

      // ---- ih-MFMA from xarea (staged last superstep) overlaps h-load flight ----
      float xin0, xin1;
      f32x4 ai0 = {0.f,0.f,0.f,0.f}, ai1 = {0.f,0.f,0.f,0.f};
      if (layer > 0) {
        const unsigned xu = *(const unsigned*)(xarea + (((ub * 1024) + kpglob * 4) ^ ((ub & 7) << 4)));
        xin0 = bflo(xu); xin1 = bfhi(xu);
#pragma unroll
        for (int kk = 0; kk < 16; ++kk) {
          const i32x4 x0 = *(const i32x4*)(xarea + ((ab0 + kk * 64) ^ swz));
          const i32x4 x1 = *(const i32x4*)(xarea + ((ab1 + kk * 64) ^ swz));
          ai0 = __builtin_amdgcn_mfma_f32_16x16x32_bf16(__builtin_bit_cast(s16x8, x0), bfih[kk], ai0, 0, 0, 0);
          ai1 = __builtin_amdgcn_mfma_f32_16x16x32_bf16(__builtin_bit_cast(s16x8, x1), bfih[kk], ai1, 0, 0, 0);
        }
      } else { xin0 = xinc0; xin1 = xinc1; }

      // ---- tag-check + batched retry ----
      const unsigned tagh = (unsigned)t;
      for (;;) {
        bool bad = false;
#pragma unroll
        for (int it = 0; it < 32; ++it)
          if ((unsigned)(a[it] >> 32) != tagh) {
            const int q = (it + w) & 31;
            a[it] = aload(hs + q * 256 + tid);
            bad = true;
          }
        if (!bad) break;
      }

      // ---- stage h payloads into LDS (swizzled) ----
#pragma unroll
      for (int it = 0; it < 32; ++it) {
        const int q = (it + w) & 31;
        *(unsigned*)(harea + ((q * 1024 + tid * 4) ^ ((q & 7) << 4))) = (unsigned)a[it];
      }
      __syncthreads();   // (1) h staged

      f32x4 acc0, acc1;
      if (layer > 0) {
        f32x4 ah0 = {0.f,0.f,0.f,0.f}, ah1 = {0.f,0.f,0.f,0.f};
#pragma unroll
        for (int kk = 0; kk < 16; ++kk) {
          const i32x4 h0 = *(const i32x4*)(harea + ((ab0 + kk * 64) ^ swz));
          const i32x4 h1 = *(const i32x4*)(harea + ((ab1 + kk * 64) ^ swz));
          ah0 = __builtin_amdgcn_mfma_f32_16x16x32_bf16(__builtin_bit_cast(s16x8, h0), bfhh[kk], ah0, 0, 0, 0);
          ah1 = __builtin_amdgcn_mfma_f32_16x16x32_bf16(__builtin_bit_cast(s16x8, h1), bfhh[kk], ah1, 0, 0, 0);
        }
        acc0 = ai0 + ah0; acc1 = ai1 + ah1;
      } else {
        f32x4 a0a = {0.f,0.f,0.f,0.f}, a1a = {0.f,0.f,0.f,0.f};
        f32x4 a0b = {0.f,0.f,0.f,0.f}, a1b = {0.f,0.f,0.f,0.f};
#pragma unroll
        for (int kk = 0; kk < 8; ++kk) {
          const i32x4 h0a = *(const i32x4*)(harea + ((ab0 + kk * 64) ^ swz));
          const i32x4 h1a = *(const i32x4*)(harea + ((ab1 + kk * 64) ^ swz));
          const i32x4 h0b = *(const i32x4*)(harea + ((ab0 + (kk + 8) * 64) ^ swz));
          const i32x4 h1b = *(const i32x4*)(harea + ((ab1 + (kk + 8) * 64) ^ swz));
          a0a = __builtin_amdgcn_mfma_f32_16x16x32_bf16(__builtin_bit_cast(s16x8, h0a), bfhh[kk], a0a, 0, 0, 0);
          a1a = __builtin_amdgcn_mfma_f32_16x16x32_bf16(__builtin_bit_cast(s16x8, h1a), bfhh[kk], a1a, 0, 0, 0);
          a0b = __builtin_amdgcn_mfma_f32_16x16x32_bf16(__builtin_bit_cast(s16x8, h0b), bfhh[kk + 8], a0b, 0, 0, 0);
          a1b = __builtin_amdgcn_mfma_f32_16x16x32_bf16(__builtin_bit_cast(s16x8, h1b), bfhh[kk + 8], a1b, 0, 0, 0);
        }
        acc0 = a0a + a0b; acc1 = a1a + a1b;
      }
      __syncthreads();   // (2) harea reads done (gacc may alias staged rows 16-25)
      {
        float* gp = gacc + (wv * 16 + rA) * 36 + kg2 * 4;
        *(f32x4*)gp        = acc0;
        *(f32x4*)(gp + 16) = acc1;
      }
      __syncthreads();   // (3)

      float pre[4][2];
#pragma unroll
      for (int g = 0; g < 4; ++g)
#pragma unroll
        for (int c = 0; c < 2; ++c) {
          float vv = gacc[(g * 16 + 2 * jp + c) * 36 + ub] + bs[g][c];
          if (layer == 0) vv += ((const float*)smem)[(g * 32 + ub) * 16 + 2 * jp + c];
          pre[g][c] = vv;
        }

      float i0 = sigm(pre[0][0]), ff0 = sigm(pre[1][0]), g0 = tanh_(pre[2][0]), o0 = sigm(pre[3][0]);
      creg0 = ff0 * creg0 + i0 * g0;
      float h0 = o0 * tanh_(creg0);
      float i1 = sigm(pre[0][1]), ff1 = sigm(pre[1][1]), g1 = tanh_(pre[2][1]), o1 = sigm(pre[3][1]);
      creg1 = ff1 * creg1 + i1 * g1;
      float h1 = o1 * tanh_(creg1);
      const float out0 = h0 + xin0, out1 = h1 + xin1;
      const unsigned long long tago = ((unsigned long long)(unsigned)(t + 1)) << 32;

      if (layer < 5) {
        float sP  = out0 + out1;
        float ssP = out0 * out0 + out1 * out1;
#pragma unroll
        for (int m = 1; m < 8; m <<= 1) { sP += __shfl_xor(sP, m, 64); ssP += __shfl_xor(ssP, m, 64); }
        astore(Roll + layer * 32768 + (size_t)(t & 3) * 8192 + ub * 256 + kpglob,
               tago | pack2bf(out0, out1));
        if (jp == 0) {
          const size_t pi = layer * 4096 + (size_t)(t & 3) * 1024 + w * 32 + ub;
          astore(PartS + pi, tago | __float_as_uint(sP));
          astore(PartQ + pi, tago | __float_as_uint(ssP));
        }
      } else {
        RB[((size_t)ub * 2048 + t) * 256 + kpglob] = pack2bf(out0, out1);
      }
      astore(HstL + (size_t)((t + 1) & 1) * 8192 + (ub << 8) + kpglob, tago | pack2bf(h0, h1));
    }

    // ===== phase D: prefetch + LN-stage next input row =====
    const int r = s + 1 + tbase;
    if (layer > 0 && 0 <= r && r < 2048) {
      const unsigned long long* RollC = Roll + (layer - 1) * 32768 + (size_t)(r & 3) * 8192;
      unsigned long long xr[32];
#pragma unroll
      for (int i = 0; i < 32; ++i) {
        const int q = (i + w) & 31;
        xr[i] = aload(RollC + q * 256 + tid);
      }
      const int b = tid & 31, w8 = tid >> 5;
      const unsigned long long* PSc = PartS + (layer - 1) * 4096 + (size_t)(r & 3) * 1024;
      const unsigned long long* PQc = PartQ + (layer - 1) * 4096 + (size_t)(r & 3) * 1024;
      unsigned long long ps[4], pq[4];
#pragma unroll
      for (int k = 0; k < 4; ++k) {
        ps[k] = aload(PSc + (w8 + 8 * k) * 32 + b);
        pq[k] = aload(PQc + (w8 + 8 * k) * 32 + b);
      }
      const unsigned tagr = (unsigned)(r + 1);
      for (;;) {
        bool bad = false;
#pragma unroll
        for (int i = 0; i < 32; ++i)
          if ((unsigned)(xr[i] >> 32) != tagr) {
            const int q = (i + w) & 31;
            xr[i] = aload(RollC + q * 256 + tid);
            bad = true;
          }
#pragma unroll
        for (int k = 0; k < 4; ++k) {
          if ((unsigned)(ps[k] >> 32) != tagr) { ps[k] = aload(PSc + (w8 + 8 * k) * 32 + b); bad = true; }
          if ((unsigned)(pq[k] >> 32) != tagr) { pq[k] = aload(PQc + (w8 + 8 * k) * 32 + b); bad = true; }
        }
        if (!bad) break;
      }
      float s4 = 0.f, ss4 = 0.f;
#pragma unroll
      for (int k = 0; k < 4; ++k) {
        s4  += __uint_as_float((unsigned)ps[k]);
        ss4 += __uint_as_float((unsigned)pq[k]);
      }
      float* scr = (float*)harea;            // [8][32][2], disjoint from gacc(+16K)
      scr[(w8 * 32 + b) * 2]     = s4;
      scr[(w8 * 32 + b) * 2 + 1] = ss4;
      __syncthreads();   // D1
      float* stats = (float*)(harea + 2048); // [32][2] = {mu, rs}
      if (tid < 32) {
        const float* sc = (const float*)harea;
        float ssum = 0.f, sssum = 0.f;
#pragma unroll
        for (int k = 0; k < 8; ++k) { ssum += sc[(k * 32 + tid) * 2]; sssum += sc[(k * 32 + tid) * 2 + 1]; }
        const float mu = ssum * (1.f / 512.f);
        float var = sssum * (1.f / 512.f) - mu * mu;
        stats[tid * 2]     = mu;
        stats[tid * 2 + 1] = rsqrtf(var + 1e-5f);
      }
      __syncthreads();   // D2
#pragma unroll
      for (int i = 0; i < 32; ++i) {
        const int q = (i + w) & 31;
        const float mu = stats[q * 2], rs = stats[q * 2 + 1];
        const unsigned u = (unsigned)xr[i];
        const float av = (bflo(u) - mu) * rs * sc0  + bi0;
        const float bv = (bfhi(u) - mu) * rs * sc1v + bi1;
        *(unsigned*)(xarea + ((q * 1024 + tid * 4) ^ ((q & 7) << 4))) = pack2bf(av, bv);
      }
    }

    // ---- publish progress (consumers certify Roll rows <= t+1 consumed) ----
    if (layer > 0 && act && tid == 0)
      __hip_atomic_store(Prog + layer * 32 + w, (unsigned)(t + 1),
                         __ATOMIC_RELAXED, __HIP_MEMORY_SCOPE_AGENT);

    __syncthreads();   // (5) xarea/LDS writes visible before next iteration
  }
}

// ---------------- fused final LayerNorm + output head ----------------
__global__ __launch_bounds__(256) void k_lnout(const unsigned* __restrict__ Rin,
                                               const float* __restrict__ lnS,
                                               const float* __restrict__ lnB,
                                               const float* __restrict__ ow,
                                               const float* __restrict__ ob,
                                               float* __restrict__ y) {
  int row  = blockIdx.x * 4 + (threadIdx.x >> 6);   // b*T + t
  int lane = threadIdx.x & 63;
  const i32x4 v = *(const i32x4*)(Rin + (size_t)row * 256 + lane * 4);
  float xv[8];
#pragma unroll
  for (int j = 0; j < 4; ++j) {
    unsigned u = (unsigned)v[j];
    xv[2*j]   = bflo(u);
    xv[2*j+1] = bfhi(u);
  }
  float s = 0.f, s2 = 0.f;
#pragma unroll
  for (int j = 0; j < 8; ++j) { s += xv[j]; s2 += xv[j] * xv[j]; }
#pragma unroll
  for (int m = 1; m < 64; m <<= 1) { s += __shfl_xor(s, m, 64); s2 += __shfl_xor(s2, m, 64); }
  float mu  = s * (1.f / 512.f);
  float var = s2 * (1.f / 512.f) - mu * mu;
  float rs  = rsqrtf(var + 1e-5f);
  const float* Sp = lnS + 5 * 512 + lane * 8;
  const float* Bp = lnB + 5 * 512 + lane * 8;
  const float* wp = ow + lane * 8;
  float acc = 0.f;
#pragma unroll
  for (int j = 0; j < 8; ++j)
    acc += ((xv[j] - mu) * rs * Sp[j] + Bp[j]) * wp[j];
#pragma unroll
  for (int m = 1; m < 64; m <<= 1) acc += __shfl_xor(acc, m, 64);
  if (lane == 0) y[row] = acc + ob[0];
}

extern "C" void kernel_launch(void* const* d_in, const int* in_sizes, int n_in,
                              void* d_out, int out_size, void* d_ws, size_t ws_size,
                              hipStream_t stream) {
  (void)in_sizes; (void)n_in; (void)out_size; (void)ws_size;
  const float* x   = (const float*)d_in[0];
  const float* ipw = (const float*)d_in[1];
  const float* ipb = (const float*)d_in[2];
  const float* Wih = (const float*)d_in[3];
  const float* Whh = (const float*)d_in[4];
  const float* bih = (const float*)d_in[5];
  const float* bhh = (const float*)d_in[6];
  const float* lnS = (const float*)d_in[7];
  const float* lnB = (const float*)d_in[8];
  const float* ow  = (const float*)d_in[9];
  const float* ob  = (const float*)d_in[10];
  float* y = (float*)d_out;

  char* ws = (char*)d_ws;
  unsigned* Prog            = (unsigned*)ws;                         // 768 B
  float* XP                 = (float*)(ws + 4096);                   // 64 KB
  float* XG0                = (float*)(ws + 69632);                  // 256 KB
  unsigned long long* Hst   = (unsigned long long*)(ws + 331776);    // 768 KB
  unsigned long long* Roll  = (unsigned long long*)(ws + 1118208);   // 1.25 MB
  unsigned long long* PartS = (unsigned long long*)(ws + 2428928);   // 160 KB
  unsigned long long* PartQ = (unsigned long long*)(ws + 2592768);   // 160 KB
  unsigned* RB              = (unsigned*)(ws + 4194304);             // 67.1 MB

  hipMemsetAsync(Prog, 0, 768, stream);
  hipMemsetAsync(Hst, 0, 786432, stream);
  k_inproj<<<64, 256, 0, stream>>>(x, ipw, ipb, XP);
  k_xg0<<<256, 256, 0, stream>>>(XP, Wih, bih, XG0);
  k_pipe<<<192, 256, 0, stream>>>(Wih, Whh, bih, bhh, lnS, lnB, XG0, XP,
                                  Hst, Roll, PartS, PartQ, RB, Prog);
  k_lnout<<<16384, 256, 0, stream>>>(RB, lnS, lnB, ow, ob, y);
}